// Round 5
// baseline (362.840 us; speedup 1.0000x reference)
//
#include <hip/hip_runtime.h>
#include <math.h>

#define B_    2
#define L_    2048
#define H_    16
#define D_    128
#define S_    40
#define NTOP_ 40
#define NCH_  8        // key chunks for attention
#define CHK_  256      // keys per chunk (attention)
#define CH2_  8        // key chunks for sampleM
#define CROW_ 256      // K rows per sampleM chunk
#define KSTRIDE 132    // floats per staged K row (128 + 4 pad -> bank spread)

#define SCALE_ 0.08838834764831843f  // 1/sqrt(128)

// ---------------- K1: LDS-staged sampleM partials + V mean -------------------
// Blocks 0..31: V mean per bh (1024 thr, full L) -> vmean. Block 0 zeroes cnt.
// Blocks 32..287: sample chunks. sb=bid-32; xcd=sb&7 owns bh in [xcd*4,xcd*4+4)
//   (dispatch round-robin pins the 8 chunk-blocks of a bh + its Q slice to one
//   XCD's L2). Stage K rows [c0,c0+256) of (b,h) into LDS once; every wave
//   walks q=wv..2047 step 16, ballot-compacts the in-chunk samples, gathers
//   them from LDS (8-lane group per sample), emits per-chunk (max,sum).
__global__ __launch_bounds__(1024) void k1_sample_vmean(const float* __restrict__ Q,
                                                        const float* __restrict__ K,
                                                        const float* __restrict__ V,
                                                        const int* __restrict__ idx,
                                                        float* __restrict__ pmaxc,
                                                        float* __restrict__ psumc,
                                                        float* __restrict__ vmean,
                                                        int* __restrict__ cnt) {
    __shared__ float Ks[CROW_ * KSTRIDE];   // 135168 B (also reused as reduction)
    __shared__ int   wlist[16][44];
    const int bid = blockIdx.x;
    const int t   = threadIdx.x;

    if (bid < 32) {
        // ---- V mean for bh = bid ----
        if (bid == 0 && t < 32) cnt[t] = 0;
        const int bh = bid;
        const int h  = bh & (H_ - 1);
        const int b  = bh >> 4;
        const int d  = t & (D_ - 1);
        const int sub = t >> 7;             // 0..7
        float acc = 0.0f;
        for (int l = sub; l < L_; l += 8)
            acc += V[((size_t)(b * L_ + l) * H_ + h) * D_ + d];
        float* red = Ks;
        red[t] = acc;
        __syncthreads();
        if (t < 512) red[t] += red[t + 512];
        __syncthreads();
        if (t < 256) red[t] += red[t + 256];
        __syncthreads();
        if (t < 128) vmean[bh * D_ + t] = (red[t] + red[t + 128]) * (1.0f / L_);
        return;
    }

    const int sb    = bid - 32;
    const int xcd   = sb & 7;
    const int sub32 = sb >> 3;              // 0..31
    const int bh    = (xcd << 2) + (sub32 & 3);
    const int chunk = sub32 >> 2;           // 0..7
    const int c0    = chunk * CROW_;
    const int h     = bh & (H_ - 1);
    const int b     = bh >> 4;

    // ---- stage K[c0..c0+256) rows into LDS (stride 132 floats) ----
    {
        const int sub8 = t & 7;             // float4 slot within a 128B j-block
        const int rr   = t >> 3;            // 0..127
        #pragma unroll
        for (int half = 0; half < 2; ++half) {
            const int r = half * 128 + rr;
            const float4* src = (const float4*)(K + ((size_t)(b * L_ + c0 + r) * H_ + h) * D_);
            #pragma unroll
            for (int j = 0; j < 4; ++j) {
                const int f4 = j * 8 + sub8;
                *(float4*)&Ks[r * KSTRIDE + f4 * 4] = src[f4];
            }
        }
    }
    __syncthreads();

    const int wv   = t >> 6;                // wave 0..15
    const int lane = t & 63;
    const int g    = lane >> 3;             // sample group 0..7
    const int sub  = lane & 7;              // float4 within D

    for (int q = wv; q < L_; q += 16) {
        // which of q's 40 samples fall in this chunk?
        int  idxv = 0;
        bool inch = false;
        if (lane < S_) {
            idxv = idx[q * S_ + lane];
            inch = (idxv >= c0) && (idxv < c0 + CROW_);
        }
        const unsigned long long mask = __ballot(inch);
        const int scnt = __popcll(mask);
        if (inch) {
            const int pos = __popcll(mask & ((1ull << lane) - 1ull));
            wlist[wv][pos] = idxv - c0;
        }
        asm volatile("s_waitcnt lgkmcnt(0)" ::: "memory");

        const float4* Qr = (const float4*)(Q + ((size_t)(b * L_ + q) * H_ + h) * D_);
        const float4 qv0 = Qr[0 * 8 + sub];
        const float4 qv1 = Qr[1 * 8 + sub];
        const float4 qv2 = Qr[2 * 8 + sub];
        const float4 qv3 = Qr[3 * 8 + sub];

        float smax = -INFINITY, ssum = 0.0f;
        for (int base = 0; base < scnt; base += 8) {
            const int  rk  = base + g;
            const bool act = rk < scnt;
            const int  row = act ? wlist[wv][rk] : 0;
            const float* kr = &Ks[row * KSTRIDE];
            float4 kv = *(const float4*)&kr[(0 * 8 + sub) * 4];
            float p  = qv0.x * kv.x + qv0.y * kv.y + qv0.z * kv.z + qv0.w * kv.w;
            kv = *(const float4*)&kr[(1 * 8 + sub) * 4];
            p += qv1.x * kv.x + qv1.y * kv.y + qv1.z * kv.z + qv1.w * kv.w;
            kv = *(const float4*)&kr[(2 * 8 + sub) * 4];
            p += qv2.x * kv.x + qv2.y * kv.y + qv2.z * kv.z + qv2.w * kv.w;
            kv = *(const float4*)&kr[(3 * 8 + sub) * 4];
            p += qv3.x * kv.x + qv3.y * kv.y + qv3.z * kv.z + qv3.w * kv.w;
            p += __shfl_xor(p, 1);
            p += __shfl_xor(p, 2);
            p += __shfl_xor(p, 4);
            if (act) { smax = fmaxf(smax, p); ssum += p; }
        }
        #pragma unroll
        for (int o = 8; o < 64; o <<= 1) {
            smax = fmaxf(smax, __shfl_xor(smax, o));
            ssum += __shfl_xor(ssum, o);
        }
        if (lane == 0) {
            pmaxc[((size_t)bh * CH2_ + chunk) * L_ + q] = smax;
            psumc[((size_t)bh * CH2_ + chunk) * L_ + q] = ssum;
        }
    }
}

// ---------------- K2: fused rank (top-40) + broadcast fill -------------------
// blocks 0..255: fold the 8 chunk partials into M, rank-select per (b,h):
//   rank(e) = #{j: M[j]>M[e]} + #{j<e: M[j]==M[e]}; selected iff rank < 40
//   (matches jax.lax.top_k SET). blocks 256..2303: fill out with vmean.
__global__ __launch_bounds__(256) void k2_rank_fill(const float* __restrict__ pmaxc,
                                                    const float* __restrict__ psumc,
                                                    const float* __restrict__ vmean,
                                                    int* __restrict__ cnt,
                                                    int* __restrict__ topk,
                                                    float* __restrict__ out) {
    __shared__ float ml[L_];
    const int bid = blockIdx.x;
    const int t   = threadIdx.x;

    if (bid < 256) {
        const int bh    = bid >> 3;
        const int chunk = bid & 7;
        for (int i = t; i < L_; i += 256) {
            float m = -INFINITY, s = 0.0f;
            #pragma unroll
            for (int c = 0; c < CH2_; ++c) {
                m = fmaxf(m, pmaxc[((size_t)bh * CH2_ + c) * L_ + i]);
                s += psumc[((size_t)bh * CH2_ + c) * L_ + i];
            }
            ml[i] = m - s * (1.0f / L_);
        }
        __syncthreads();
        const int e = chunk * 256 + t;
        const float me = ml[e];
        const float4* m4 = (const float4*)ml;
        int gt = 0, eqb = 0;
        for (int j4 = 0; j4 < L_ / 4; ++j4) {
            const float4 v = m4[j4];
            const int j = j4 * 4;
            gt  += (v.x > me) + (v.y > me) + (v.z > me) + (v.w > me);
            eqb += ((v.x == me) & (j < e)) + ((v.y == me) & ((j + 1) < e)) +
                   ((v.z == me) & ((j + 2) < e)) + ((v.w == me) & ((j + 3) < e));
        }
        if (gt + eqb < NTOP_) {
            const int pos = atomicAdd(&cnt[bh], 1);
            topk[bh * NTOP_ + pos] = e;
        }
    } else {
        const int fb = bid - 256;            // 0..2047
        const int bh = fb >> 6;
        const int sl = fb & 63;              // 64 slices of 32 q-rows
        const int h  = bh & (H_ - 1);
        const int b  = bh >> 4;
        const float4 vm4 = *(const float4*)&vmean[bh * D_ + (t & 31) * 4];
        float4* out4 = (float4*)out;
        const int q0 = sl * 32;
        #pragma unroll
        for (int k = 0; k < 4; ++k) {
            const int j = k * 256 + t;
            const int r = j >> 5;            // row within slice, col = t&31
            out4[((size_t)(b * L_ + q0 + r) * H_ + h) * 32 + (t & 31)] = vm4;
        }
    }
}

// ---------------- K3: chunked scores + partial softmax + partial PV ----------
// Block = (bh, kc, uh): uh = half of the 40 selected queries (20 each).
__global__ __launch_bounds__(256) void k_scorepv(const float* __restrict__ Q,
                                                 const float* __restrict__ K,
                                                 const float* __restrict__ V,
                                                 const int* __restrict__ topk,
                                                 float* __restrict__ pmax,
                                                 float* __restrict__ psum,
                                                 float* __restrict__ pout) {
    __shared__ float Qs[20 * D_];           // 10 KB
    __shared__ float S[20 * 260];           // 20.3 KB
    __shared__ float mrow[20];
    __shared__ int   tq[20];
    const int bid = blockIdx.x;             // (bh*8 + kc)*2 + uh
    const int uh  = bid & 1;
    const int kc  = (bid >> 1) & 7;
    const int bh  = bid >> 4;
    const int h   = bh & (H_ - 1);
    const int b   = bh >> 4;
    const int t   = threadIdx.x;

    if (t < 20) tq[t] = topk[bh * NTOP_ + uh * 20 + t];
    __syncthreads();

    {
        const float4* Q4 = (const float4*)Q;
        float4* Qs4 = (float4*)Qs;
        #pragma unroll
        for (int it = 0; it < 3; ++it) {
            const int i = it * 256 + t;
            if (i < 640) {
                const int u = i >> 5, dc = i & 31;
                Qs4[i] = Q4[((size_t)(b * L_ + tq[u]) * H_ + h) * 32 + dc];
            }
        }
    }
    __syncthreads();

    {
        float acc[20];
        #pragma unroll
        for (int u = 0; u < 20; ++u) acc[u] = 0.0f;
        const float4* Kb = (const float4*)K + ((size_t)(b * L_ + kc * CHK_ + t) * H_ + h) * 32;
        const float4* Qs4 = (const float4*)Qs;
        for (int dc = 0; dc < 32; ++dc) {
            const float4 kv = Kb[dc];
            #pragma unroll
            for (int u = 0; u < 20; ++u) {
                const float4 qv = Qs4[u * 32 + dc];
                acc[u] += qv.x * kv.x + qv.y * kv.y + qv.z * kv.z + qv.w * kv.w;
            }
        }
        #pragma unroll
        for (int u = 0; u < 20; ++u) S[u * 260 + t] = acc[u] * SCALE_;
    }
    __syncthreads();

    {
        const int w = t >> 6, lane = t & 63;
        #pragma unroll
        for (int uu = 0; uu < 5; ++uu) {
            const int u = w * 5 + uu;
            const float* Sr = S + u * 260;
            float v = fmaxf(fmaxf(Sr[lane], Sr[lane + 64]),
                            fmaxf(Sr[lane + 128], Sr[lane + 192]));
            #pragma unroll
            for (int o = 1; o < 64; o <<= 1) v = fmaxf(v, __shfl_xor(v, o, 64));
            if (lane == 0) mrow[u] = v;
        }
    }
    __syncthreads();

    #pragma unroll
    for (int u = 0; u < 20; ++u) S[u * 260 + t] = __expf(S[u * 260 + t] - mrow[u]);
    __syncthreads();

    {
        const int w = t >> 6, lane = t & 63;
        #pragma unroll
        for (int uu = 0; uu < 5; ++uu) {
            const int u = w * 5 + uu;
            const float* Sr = S + u * 260;
            float v = Sr[lane] + Sr[lane + 64] + Sr[lane + 128] + Sr[lane + 192];
            #pragma unroll
            for (int o = 1; o < 64; o <<= 1) v += __shfl_xor(v, o, 64);
            if (lane == 0) {
                psum[(bh * NCH_ + kc) * NTOP_ + uh * 20 + u] = v;
                pmax[(bh * NCH_ + kc) * NTOP_ + uh * 20 + u] = mrow[u];
            }
        }
    }

    {
        const int d  = t & (D_ - 1);
        const int g  = t >> 7;
        const int u0 = g * 10;
        float acc2[10];
        #pragma unroll
        for (int u = 0; u < 10; ++u) acc2[u] = 0.0f;
        const float* Vb = V + ((size_t)(b * L_ + kc * CHK_) * H_ + h) * D_ + d;
        for (int kq = 0; kq < CHK_ / 4; ++kq) {
            const float v0 = Vb[(size_t)(kq * 4 + 0) * (H_ * D_)];
            const float v1 = Vb[(size_t)(kq * 4 + 1) * (H_ * D_)];
            const float v2 = Vb[(size_t)(kq * 4 + 2) * (H_ * D_)];
            const float v3 = Vb[(size_t)(kq * 4 + 3) * (H_ * D_)];
            #pragma unroll
            for (int u = 0; u < 10; ++u) {
                const float4 p = *(const float4*)&S[(u0 + u) * 260 + kq * 4];
                acc2[u] += p.x * v0 + p.y * v1 + p.z * v2 + p.w * v3;
            }
        }
        float* pb = pout + (((size_t)(bh * NCH_ + kc)) * NTOP_ + uh * 20 + u0) * D_ + d;
        #pragma unroll
        for (int u = 0; u < 10; ++u) pb[(size_t)u * D_] = acc2[u];
    }
}

// ---------------- K4: combine chunk partials, scatter to out -----------------
__global__ __launch_bounds__(128) void k_comb(const float* __restrict__ pmax,
                                              const float* __restrict__ psum,
                                              const float* __restrict__ pout,
                                              const int* __restrict__ topk,
                                              float* __restrict__ out) {
    const int bid = blockIdx.x;          // bh*40 + u
    const int bh  = bid / NTOP_;
    const int u   = bid - bh * NTOP_;
    const int h   = bh & (H_ - 1);
    const int b   = bh >> 4;
    const int t   = threadIdx.x;         // d

    float pm[NCH_];
    float M = -INFINITY;
    #pragma unroll
    for (int c = 0; c < NCH_; ++c) {
        pm[c] = pmax[(bh * NCH_ + c) * NTOP_ + u];
        M = fmaxf(M, pm[c]);
    }
    float ssum = 0.0f, o = 0.0f;
    #pragma unroll
    for (int c = 0; c < NCH_; ++c) {
        const float w = __expf(pm[c] - M);
        ssum += psum[(bh * NCH_ + c) * NTOP_ + u] * w;
        o += pout[((size_t)(bh * NCH_ + c) * NTOP_ + u) * D_ + t] * w;
    }
    const int qi = topk[bh * NTOP_ + u];
    out[((size_t)(b * L_ + qi) * H_ + h) * D_ + t] = o / ssum;
}

extern "C" void kernel_launch(void* const* d_in, const int* in_sizes, int n_in,
                              void* d_out, int out_size, void* d_ws, size_t ws_size,
                              hipStream_t stream) {
    const float* Q  = (const float*)d_in[0];
    const float* K  = (const float*)d_in[1];
    const float* V  = (const float*)d_in[2];
    const int* idx  = (const int*)d_in[3];
    float* out      = (float*)d_out;

    char* ws = (char*)d_ws;
    size_t off = 0;
    float* pmaxc = (float*)(ws + off); off += (size_t)32 * CH2_ * L_ * 4;  // 2 MB
    float* psumc = (float*)(ws + off); off += (size_t)32 * CH2_ * L_ * 4;  // 2 MB
    float* vmean = (float*)(ws + off); off += (size_t)4096 * 4;
    int*   cnt   = (int*)(ws + off);   off += 32 * 4;
    int*   topk  = (int*)(ws + off);   off += 1280 * 4;
    float* pmax  = (float*)(ws + off); off += (size_t)256 * 40 * 4;
    float* psum  = (float*)(ws + off); off += (size_t)256 * 40 * 4;
    float* pout  = (float*)(ws + off); off += (size_t)256 * 40 * 128 * 4;

    hipLaunchKernelGGL(k1_sample_vmean, dim3(32 + 256), dim3(1024), 0, stream,
                       Q, K, V, idx, pmaxc, psumc, vmean, cnt);
    hipLaunchKernelGGL(k2_rank_fill,    dim3(256 + 2048), dim3(256), 0, stream,
                       pmaxc, psumc, vmean, cnt, topk, out);
    hipLaunchKernelGGL(k_scorepv,       dim3(512),  dim3(256), 0, stream,
                       Q, K, V, topk, pmax, psum, pout);
    hipLaunchKernelGGL(k_comb,          dim3(1280), dim3(128), 0, stream,
                       pmax, psum, pout, topk, out);
}

// Round 6
// 304.777 us; speedup vs baseline: 1.1905x; 1.1905x over previous
//
#include <hip/hip_runtime.h>
#include <math.h>

#define B_    2
#define L_    2048
#define H_    16
#define D_    128
#define S_    40
#define NTOP_ 40
#define NCH_  8        // key chunks for attention
#define CHK_  256      // keys per chunk (attention)
#define VCH_  32       // L chunks for vmean
#define QTSZ_ 256      // q-tile size for sampleM
#define LCAP_ 32       // list capacity per (qtile, ki) bucket

#define SCALE_ 0.08838834764831843f  // 1/sqrt(128)

// ---------------- kA: inverse-list build + V partial sums --------------------
// blocks 0..319: each thread owns one (q,s) pair; bins q into bucket
//   (qtile(q), idx[q,s]). Lists are shared across all (b,h) since index_sample
//   is the same for every head. cntA zeroed by hipMemsetAsync beforehand.
// blocks 320..1343: r4 vpartial (V chunk sums).
__global__ __launch_bounds__(256) void kA_build_vpart(const float* __restrict__ V,
                                                      const int* __restrict__ idx,
                                                      unsigned int* __restrict__ cntA,
                                                      unsigned char* __restrict__ listA,
                                                      float* __restrict__ vpart) {
    const int bid = blockIdx.x;
    const int t   = threadIdx.x;
    if (bid < 320) {
        const int e  = bid * 256 + t;        // 0..81919
        const int q  = e / S_;
        const int ki = idx[e];
        const int bucket = (q >> 8) * L_ + ki;
        const unsigned int pos = atomicAdd(&cntA[bucket], 1u);
        if (pos < LCAP_) listA[(size_t)bucket * LCAP_ + pos] = (unsigned char)(q & 255);
    } else {
        __shared__ float red[256];
        const int vbid = bid - 320;          // bh*VCH_ + lc
        const int bh  = vbid >> 5;
        const int lc  = vbid & (VCH_ - 1);
        const int h   = bh & (H_ - 1);
        const int b   = bh >> 4;
        const int d   = t & (D_ - 1);
        const int sub = t >> 7;
        float acc = 0.0f;
        const int l0 = lc * (L_ / VCH_);     // 64 rows per chunk
        for (int l = l0 + sub; l < l0 + L_ / VCH_; l += 2)
            acc += V[((size_t)(b * L_ + l) * H_ + h) * D_ + d];
        red[t] = acc;
        __syncthreads();
        if (t < D_) vpart[(size_t)vbid * D_ + t] = red[t] + red[t + 128];
    }
}

// ---------------- kB: dedup-LDS sampleM ------------------------------------
// Block = (bh, qtile): stage 256 Q rows (128 KB) in LDS once; stream ALL K
// rows coalesced (wave loads 2 rows per instr: lane = (row01, float4-of-D));
// for each ki, walk its precomputed q-list, dot LDS-Q with reg-K (32-lane
// half-wave per pair), fold into per-q running max (monotone-int atomicMax,
// order-independent) and sum (LDS float atomicAdd). K read ONCE per block
// (~1 MB, XCD-pinned -> L2-resident across the 8 qtile-blocks of each bh).
__global__ __launch_bounds__(1024) void kB_sample(const float* __restrict__ Q,
                                                  const float* __restrict__ K,
                                                  const unsigned int* __restrict__ cntA,
                                                  const unsigned char* __restrict__ listA,
                                                  float* __restrict__ M) {
    __shared__ float Qs[QTSZ_ * D_];          // 128 KB
    __shared__ unsigned int amaxL[QTSZ_];
    __shared__ float asumL[QTSZ_];
    const int bid = blockIdx.x;
    const int xcd = bid & 7;
    const int s32 = bid >> 3;                 // 0..31
    const int bh  = (xcd << 2) + (s32 & 3);   // 4 bh per XCD
    const int qt  = s32 >> 2;                 // 0..7
    const int h   = bh & (H_ - 1);
    const int b   = bh >> 4;
    const int t   = threadIdx.x;
    const int q0  = qt * QTSZ_;

    const float4* Q4 = (const float4*)Q;
    const float4* K4 = (const float4*)K;
    float4* Qs4 = (float4*)Qs;
    #pragma unroll
    for (int j = 0; j < 8; ++j) {
        const int g   = j * 1024 + t;         // 0..8191
        const int row = g >> 5, c = g & 31;
        Qs4[g] = Q4[((size_t)(b * L_ + q0 + row) * H_ + h) * 32 + c];
    }
    if (t < QTSZ_) { amaxL[t] = 0x007FFFFFu; asumL[t] = 0.0f; }  // enc(-inf)
    __syncthreads();

    const int wv   = t >> 6;                  // 0..15
    const int lane = t & 63;
    const int half = lane >> 5;
    const int sub  = lane & 31;
    const unsigned int qtbase = qt * L_;

    for (int kb = 2 * wv; kb < L_; kb += 32) {
        const int ki = kb + half;
        const float4 kv = K4[((size_t)(b * L_ + ki) * H_ + h) * 32 + sub];
        unsigned int cl = (lane < 2) ? cntA[qtbase + kb + lane] : 0u;
        int c0 = __shfl((int)cl, 0);
        int c1 = __shfl((int)cl, 1);
        c0 = min(c0, LCAP_); c1 = min(c1, LCAP_);
        const int myc = half ? c1 : c0;
        int ent = 0;
        if (sub < myc) ent = listA[(size_t)(qtbase + ki) * LCAP_ + sub];
        const int jmax = max(c0, c1);
        for (int j = 0; j < jmax; ++j) {
            const int qrow = __shfl(ent, (half << 5) + j);
            const bool act = j < myc;
            const float4 qv = Qs4[qrow * 32 + sub];
            float p = qv.x * kv.x + qv.y * kv.y + qv.z * kv.z + qv.w * kv.w;
            p += __shfl_xor(p, 1);
            p += __shfl_xor(p, 2);
            p += __shfl_xor(p, 4);
            p += __shfl_xor(p, 8);
            p += __shfl_xor(p, 16);
            if (act && sub == 0) {
                const unsigned int pb = __float_as_uint(p);
                const unsigned int pe = (pb & 0x80000000u) ? ~pb : (pb | 0x80000000u);
                atomicMax(&amaxL[qrow], pe);
                atomicAdd(&asumL[qrow], p);
            }
        }
    }
    __syncthreads();
    if (t < QTSZ_) {
        const unsigned int u  = amaxL[t];
        const unsigned int mb = (u & 0x80000000u) ? (u ^ 0x80000000u) : ~u;
        M[(size_t)bh * L_ + q0 + t] = __uint_as_float(mb) - asumL[t] * (1.0f / L_);
    }
}

// ---------------- K2: fused rank (top-40) + broadcast fill -------------------
// blocks 0..255: rank-select per (b,h): rank(e) = #{j: M[j]>M[e]} +
//   #{j<e: M[j]==M[e]}; selected iff rank < 40 (matches jax.lax.top_k SET).
// blocks 256..2303: fill out with vmean (folded locally from vpart).
__global__ __launch_bounds__(256) void k2_rank_fill(const float* __restrict__ M,
                                                    const float* __restrict__ vpart,
                                                    int* __restrict__ cnt,
                                                    int* __restrict__ topk,
                                                    float* __restrict__ out) {
    __shared__ float ml[L_];
    const int bid = blockIdx.x;
    const int t   = threadIdx.x;

    if (bid < 256) {
        const int bh    = bid >> 3;
        const int chunk = bid & 7;
        const float* Mrow = M + (size_t)bh * L_;
        for (int i = t; i < L_; i += 256) ml[i] = Mrow[i];
        __syncthreads();
        const int e = chunk * 256 + t;
        const float me = ml[e];
        const float4* m4 = (const float4*)ml;
        int gt = 0, eqb = 0;
        for (int j4 = 0; j4 < L_ / 4; ++j4) {
            const float4 v = m4[j4];
            const int j = j4 * 4;
            gt  += (v.x > me) + (v.y > me) + (v.z > me) + (v.w > me);
            eqb += ((v.x == me) & (j < e)) + ((v.y == me) & ((j + 1) < e)) +
                   ((v.z == me) & ((j + 2) < e)) + ((v.w == me) & ((j + 3) < e));
        }
        if (gt + eqb < NTOP_) {
            const int pos = atomicAdd(&cnt[bh], 1);
            topk[bh * NTOP_ + pos] = e;
        }
    } else {
        const int fb = bid - 256;            // 0..2047
        const int bh = fb >> 6;
        const int sl = fb & 63;              // 64 slices of 32 q-rows
        const int h  = bh & (H_ - 1);
        const int b  = bh >> 4;
        const int d    = t & (D_ - 1);
        const int half = t >> 7;
        float s = 0.0f;
        #pragma unroll
        for (int c = half * 16; c < half * 16 + 16; ++c)
            s += vpart[(size_t)(bh * VCH_ + c) * D_ + d];
        ml[t] = s;
        __syncthreads();
        if (t < D_) ml[t] = (ml[t] + ml[t + 128]) * (1.0f / L_);
        __syncthreads();
        const float4 vm4 = *(const float4*)&ml[(t & 31) * 4];
        float4* out4 = (float4*)out;
        const int q0 = sl * 32;
        #pragma unroll
        for (int k = 0; k < 4; ++k) {
            const int j = k * 256 + t;
            const int r = j >> 5;
            out4[((size_t)(b * L_ + q0 + r) * H_ + h) * 32 + (t & 31)] = vm4;
        }
    }
}

// ---------------- K3: scores (LDS-staged K) + partial softmax + partial PV ---
// Block = (bh, kc, uh). Score phase: K staged in 64-row LDS passes (stride 33
// float4 -> even bank spread); thread = (key r, u-quarter), acc[5]; Q reads
// are wave-uniform broadcasts. Kills the 64-segment global gathers.
__global__ __launch_bounds__(256) void k_scorepv(const float* __restrict__ Q,
                                                 const float* __restrict__ K,
                                                 const float* __restrict__ V,
                                                 const int* __restrict__ topk,
                                                 float* __restrict__ pmax,
                                                 float* __restrict__ psum,
                                                 float* __restrict__ pout) {
    __shared__ float Qs[20 * D_];           // 10 KB
    __shared__ float S[20 * 260];           // 20.3 KB
    __shared__ float Ks[64 * 132];          // 33.8 KB
    __shared__ float mrow[20];
    __shared__ int   tq[20];
    const int bid = blockIdx.x;             // (bh*8 + kc)*2 + uh
    const int uh  = bid & 1;
    const int kc  = (bid >> 1) & 7;
    const int bh  = bid >> 4;
    const int h   = bh & (H_ - 1);
    const int b   = bh >> 4;
    const int t   = threadIdx.x;

    if (t < 20) tq[t] = topk[bh * NTOP_ + uh * 20 + t];
    __syncthreads();

    {
        const float4* Q4 = (const float4*)Q;
        float4* Qs4 = (float4*)Qs;
        #pragma unroll
        for (int it = 0; it < 3; ++it) {
            const int i = it * 256 + t;
            if (i < 640) {
                const int u = i >> 5, dc = i & 31;
                Qs4[i] = Q4[((size_t)(b * L_ + tq[u]) * H_ + h) * 32 + dc];
            }
        }
    }
    __syncthreads();

    // scores: 4 staged passes of 64 keys
    {
        const float4* Q4 = (const float4*)Q;
        const float4* K4 = (const float4*)K;
        const float4* Qs4 = (const float4*)Qs;
        float4* Ks4 = (float4*)Ks;
        const int r = t & 63, uq = t >> 6;
        (void)Q4;
        for (int pass = 0; pass < 4; ++pass) {
            #pragma unroll
            for (int j = 0; j < 8; ++j) {
                const int g = j * 256 + t;
                const int row = g >> 5, c = g & 31;
                Ks4[row * 33 + c] =
                    K4[((size_t)(b * L_ + kc * CHK_ + pass * 64 + row) * H_ + h) * 32 + c];
            }
            __syncthreads();
            float acc[5] = {0.f, 0.f, 0.f, 0.f, 0.f};
            for (int dc = 0; dc < 32; ++dc) {
                const float4 kv = Ks4[r * 33 + dc];
                #pragma unroll
                for (int u5 = 0; u5 < 5; ++u5) {
                    const float4 qv = Qs4[(uq * 5 + u5) * 32 + dc];
                    acc[u5] += qv.x * kv.x + qv.y * kv.y + qv.z * kv.z + qv.w * kv.w;
                }
            }
            #pragma unroll
            for (int u5 = 0; u5 < 5; ++u5)
                S[(uq * 5 + u5) * 260 + pass * 64 + r] = acc[u5] * SCALE_;
            __syncthreads();
        }
    }

    {
        const int w = t >> 6, lane = t & 63;
        #pragma unroll
        for (int uu = 0; uu < 5; ++uu) {
            const int u = w * 5 + uu;
            const float* Sr = S + u * 260;
            float v = fmaxf(fmaxf(Sr[lane], Sr[lane + 64]),
                            fmaxf(Sr[lane + 128], Sr[lane + 192]));
            #pragma unroll
            for (int o = 1; o < 64; o <<= 1) v = fmaxf(v, __shfl_xor(v, o, 64));
            if (lane == 0) mrow[u] = v;
        }
    }
    __syncthreads();

    #pragma unroll
    for (int u = 0; u < 20; ++u) S[u * 260 + t] = __expf(S[u * 260 + t] - mrow[u]);
    __syncthreads();

    {
        const int w = t >> 6, lane = t & 63;
        #pragma unroll
        for (int uu = 0; uu < 5; ++uu) {
            const int u = w * 5 + uu;
            const float* Sr = S + u * 260;
            float v = Sr[lane] + Sr[lane + 64] + Sr[lane + 128] + Sr[lane + 192];
            #pragma unroll
            for (int o = 1; o < 64; o <<= 1) v += __shfl_xor(v, o, 64);
            if (lane == 0) {
                psum[(bh * NCH_ + kc) * NTOP_ + uh * 20 + u] = v;
                pmax[(bh * NCH_ + kc) * NTOP_ + uh * 20 + u] = mrow[u];
            }
        }
    }

    {
        const int d  = t & (D_ - 1);
        const int g  = t >> 7;
        const int u0 = g * 10;
        float acc2[10];
        #pragma unroll
        for (int u = 0; u < 10; ++u) acc2[u] = 0.0f;
        const float* Vb = V + ((size_t)(b * L_ + kc * CHK_) * H_ + h) * D_ + d;
        for (int kq = 0; kq < CHK_ / 4; ++kq) {
            const float v0 = Vb[(size_t)(kq * 4 + 0) * (H_ * D_)];
            const float v1 = Vb[(size_t)(kq * 4 + 1) * (H_ * D_)];
            const float v2 = Vb[(size_t)(kq * 4 + 2) * (H_ * D_)];
            const float v3 = Vb[(size_t)(kq * 4 + 3) * (H_ * D_)];
            #pragma unroll
            for (int u = 0; u < 10; ++u) {
                const float4 p = *(const float4*)&S[(u0 + u) * 260 + kq * 4];
                acc2[u] += p.x * v0 + p.y * v1 + p.z * v2 + p.w * v3;
            }
        }
        float* pb = pout + (((size_t)(bh * NCH_ + kc)) * NTOP_ + uh * 20 + u0) * D_ + d;
        #pragma unroll
        for (int u = 0; u < 10; ++u) pb[(size_t)u * D_] = acc2[u];
    }
}

// ---------------- K4: combine chunk partials, scatter to out -----------------
__global__ __launch_bounds__(128) void k_comb(const float* __restrict__ pmax,
                                              const float* __restrict__ psum,
                                              const float* __restrict__ pout,
                                              const int* __restrict__ topk,
                                              float* __restrict__ out) {
    const int bid = blockIdx.x;          // bh*40 + u
    const int bh  = bid / NTOP_;
    const int u   = bid - bh * NTOP_;
    const int h   = bh & (H_ - 1);
    const int b   = bh >> 4;
    const int t   = threadIdx.x;         // d

    float pm[NCH_];
    float M = -INFINITY;
    #pragma unroll
    for (int c = 0; c < NCH_; ++c) {
        pm[c] = pmax[(bh * NCH_ + c) * NTOP_ + u];
        M = fmaxf(M, pm[c]);
    }
    float ssum = 0.0f, o = 0.0f;
    #pragma unroll
    for (int c = 0; c < NCH_; ++c) {
        const float w = __expf(pm[c] - M);
        ssum += psum[(bh * NCH_ + c) * NTOP_ + u] * w;
        o += pout[((size_t)(bh * NCH_ + c) * NTOP_ + u) * D_ + t] * w;
    }
    const int qi = topk[bh * NTOP_ + u];
    out[((size_t)(b * L_ + qi) * H_ + h) * D_ + t] = o / ssum;
}

extern "C" void kernel_launch(void* const* d_in, const int* in_sizes, int n_in,
                              void* d_out, int out_size, void* d_ws, size_t ws_size,
                              hipStream_t stream) {
    const float* Q  = (const float*)d_in[0];
    const float* K  = (const float*)d_in[1];
    const float* V  = (const float*)d_in[2];
    const int* idx  = (const int*)d_in[3];
    float* out      = (float*)d_out;

    char* ws = (char*)d_ws;
    size_t off = 0;
    float* Mws   = (float*)(ws + off); off += (size_t)65536 * 4;            // 256 KB
    float* vpart = (float*)(ws + off); off += (size_t)1024 * 128 * 4;       // 512 KB
    unsigned int* cntA = (unsigned int*)(ws + off); off += (size_t)8 * L_ * 4;  // 64 KB
    int*   rcnt  = (int*)(ws + off);   off += 32 * 4;                       // adjacent to cntA
    int*   topk  = (int*)(ws + off);   off += 1280 * 4;
    unsigned char* listA = (unsigned char*)(ws + off); off += (size_t)8 * L_ * LCAP_; // 512 KB
    float* pmax  = (float*)(ws + off); off += (size_t)256 * 40 * 4;
    float* psum  = (float*)(ws + off); off += (size_t)256 * 40 * 4;
    float* pout  = (float*)(ws + off); off += (size_t)256 * 40 * 128 * 4;

    // zero bucket counters + rank counters (one contiguous region)
    hipMemsetAsync(cntA, 0, (size_t)8 * L_ * 4 + 32 * 4, stream);

    hipLaunchKernelGGL(kA_build_vpart, dim3(320 + 1024), dim3(256), 0, stream,
                       V, idx, cntA, listA, vpart);
    hipLaunchKernelGGL(kB_sample,      dim3(256), dim3(1024), 0, stream,
                       Q, K, cntA, listA, Mws);
    hipLaunchKernelGGL(k2_rank_fill,   dim3(256 + 2048), dim3(256), 0, stream,
                       Mws, vpart, rcnt, topk, out);
    hipLaunchKernelGGL(k_scorepv,      dim3(512),  dim3(256), 0, stream,
                       Q, K, V, topk, pmax, psum, pout);
    hipLaunchKernelGGL(k_comb,         dim3(1280), dim3(128), 0, stream,
                       pmax, psum, pout, topk, out);
}

// Round 7
// 183.920 us; speedup vs baseline: 1.9728x; 1.6571x over previous
//
#include <hip/hip_runtime.h>
#include <math.h>

#define B_    2
#define L_    2048
#define H_    16
#define D_    128
#define S_    40
#define NTOP_ 40
#define NCH_  8        // key chunks for attention
#define CHK_  256      // keys per chunk (attention)
#define VCH_  32       // L chunks for vmean

#define SCALE_ 0.08838834764831843f  // 1/sqrt(128)

#define NVP_BLKS   1024    // vpartial blocks (first, to overlap)
#define NSAMP_BLKS 16384   // sampleM: 4 rows per block (1 per wave)

// ---------------- K1: fused vpartial + sampleM -------------------------------
// blocks 0..1023: V partial sums (HBM-bound; first so they overlap the gather
//   phase). block 0 zeroes the rank counters.
// blocks 1024..17407: sampleM. One wave per q-row; 8 lanes span D (16 f/lane),
//   one 64-lane instr covers 8 samples. All 20 K-gathers are loaded into
//   explicit kv[5][4] arrays so they are ALL in flight before any reduction
//   (VGPR ~120 -> 3x the outstanding L2 requests of the VGPR=32 version).
// XCD-aware: xcd = sb&7 owns bh in [xcd*4, xcd*4+4) so each XCD's L2 holds
// its 4 MB of K slices.
__global__ __launch_bounds__(256) void k1_sample_vpart(const float* __restrict__ Q,
                                                       const float* __restrict__ K,
                                                       const float* __restrict__ V,
                                                       const int* __restrict__ idx,
                                                       float* __restrict__ M,
                                                       float* __restrict__ vpart,
                                                       int* __restrict__ cnt) {
    const int bid = blockIdx.x;
    const int t   = threadIdx.x;

    if (bid < NVP_BLKS) {
        // ---- vpartial ----
        __shared__ float red[256];
        if (bid == 0 && t < 32) cnt[t] = 0;
        const int vbid = bid;                // bh*VCH_ + lc
        const int bh  = vbid >> 5;
        const int lc  = vbid & (VCH_ - 1);
        const int h   = bh & (H_ - 1);
        const int b   = bh >> 4;
        const int d   = t & (D_ - 1);
        const int sub = t >> 7;
        float acc = 0.0f;
        const int l0 = lc * (L_ / VCH_);     // 64 rows per chunk
        for (int l = l0 + sub; l < l0 + L_ / VCH_; l += 2)
            acc += V[((size_t)(b * L_ + l) * H_ + h) * D_ + d];
        red[t] = acc;
        __syncthreads();
        if (t < D_) vpart[(size_t)vbid * D_ + t] = red[t] + red[t + 128];
        return;
    }

    const int sb   = bid - NVP_BLKS;
    const int xcd  = sb & 7;
    const int li   = sb >> 3;                 // 0..2047
    const int bh   = (xcd << 2) + (li >> 9);  // 4 bh per XCD
    const int rb   = li & 511;                // 512 row-blocks per bh
    const int wave = t >> 6;
    const int lane = t & 63;
    const int q    = rb * 4 + wave;
    const int h    = bh & (H_ - 1);
    const int b    = bh >> 4;
    const int g    = lane >> 3;               // 0..7 : sample within slot
    const int sub  = lane & 7;                // float4 within D

    const float4* Q4 = (const float4*)Q;
    const float4* K4 = (const float4*)K;
    const size_t rowQ = ((size_t)(b * L_ + q) * H_ + h) * 32;
    const float4 qv0 = Q4[rowQ + 0  + sub];
    const float4 qv1 = Q4[rowQ + 8  + sub];
    const float4 qv2 = Q4[rowQ + 16 + sub];
    const float4 qv3 = Q4[rowQ + 24 + sub];
    const size_t kbase = ((size_t)b * L_ * H_ + h) * 32 + sub;  // + ki*(H_*32)
    const int* ip = idx + q * S_;

    int kidx[5];
    #pragma unroll
    for (int s = 0; s < 5; ++s) kidx[s] = ip[s * 8 + g];

    float4 kv[5][4];   // all 20 gathers in flight together
    #pragma unroll
    for (int s = 0; s < 5; ++s) {
        const float4* kb = K4 + kbase + (size_t)kidx[s] * (H_ * 32);
        kv[s][0] = kb[0];
        kv[s][1] = kb[8];
        kv[s][2] = kb[16];
        kv[s][3] = kb[24];
    }

    float smax = -INFINITY, ssum = 0.0f;
    #pragma unroll
    for (int s = 0; s < 5; ++s) {
        float p = qv0.x * kv[s][0].x + qv0.y * kv[s][0].y + qv0.z * kv[s][0].z + qv0.w * kv[s][0].w
                + qv1.x * kv[s][1].x + qv1.y * kv[s][1].y + qv1.z * kv[s][1].z + qv1.w * kv[s][1].w
                + qv2.x * kv[s][2].x + qv2.y * kv[s][2].y + qv2.z * kv[s][2].z + qv2.w * kv[s][2].w
                + qv3.x * kv[s][3].x + qv3.y * kv[s][3].y + qv3.z * kv[s][3].z + qv3.w * kv[s][3].w;
        p += __shfl_xor(p, 1);
        p += __shfl_xor(p, 2);
        p += __shfl_xor(p, 4);
        smax = fmaxf(smax, p);
        ssum += p;
    }
    #pragma unroll
    for (int o = 8; o < 64; o <<= 1) {
        smax = fmaxf(smax, __shfl_xor(smax, o));
        ssum += __shfl_xor(ssum, o);
    }
    if (lane == 0) M[(size_t)bh * L_ + q] = smax - ssum * (1.0f / L_);
}

// ---------------- K2: fused rank (top-40) + broadcast fill -------------------
// blocks 0..255: rank-select per (b,h): rank(e) = #{j: M[j]>M[e]} +
//   #{j<e: M[j]==M[e]}; selected iff rank < 40 (matches jax.lax.top_k SET).
// blocks 256..2303: fill out with vmean (folded locally from vpart).
__global__ __launch_bounds__(256) void k2_rank_fill(const float* __restrict__ M,
                                                    const float* __restrict__ vpart,
                                                    int* __restrict__ cnt,
                                                    int* __restrict__ topk,
                                                    float* __restrict__ out) {
    __shared__ float ml[L_];
    const int bid = blockIdx.x;
    const int t   = threadIdx.x;

    if (bid < 256) {
        const int bh    = bid >> 3;
        const int chunk = bid & 7;
        const float* Mrow = M + (size_t)bh * L_;
        for (int i = t; i < L_; i += 256) ml[i] = Mrow[i];
        __syncthreads();
        const int e = chunk * 256 + t;
        const float me = ml[e];
        const float4* m4 = (const float4*)ml;
        int gt = 0, eqb = 0;
        for (int j4 = 0; j4 < L_ / 4; ++j4) {
            const float4 v = m4[j4];
            const int j = j4 * 4;
            gt  += (v.x > me) + (v.y > me) + (v.z > me) + (v.w > me);
            eqb += ((v.x == me) & (j < e)) + ((v.y == me) & ((j + 1) < e)) +
                   ((v.z == me) & ((j + 2) < e)) + ((v.w == me) & ((j + 3) < e));
        }
        if (gt + eqb < NTOP_) {
            const int pos = atomicAdd(&cnt[bh], 1);
            topk[bh * NTOP_ + pos] = e;
        }
    } else {
        const int fb = bid - 256;            // 0..2047
        const int bh = fb >> 6;
        const int sl = fb & 63;              // 64 slices of 32 q-rows
        const int h  = bh & (H_ - 1);
        const int b  = bh >> 4;
        const int d    = t & (D_ - 1);
        const int half = t >> 7;
        float s = 0.0f;
        #pragma unroll
        for (int c = half * 16; c < half * 16 + 16; ++c)
            s += vpart[(size_t)(bh * VCH_ + c) * D_ + d];
        ml[t] = s;
        __syncthreads();
        if (t < D_) ml[t] = (ml[t] + ml[t + 128]) * (1.0f / L_);
        __syncthreads();
        const float4 vm4 = *(const float4*)&ml[(t & 31) * 4];
        float4* out4 = (float4*)out;
        const int q0 = sl * 32;
        #pragma unroll
        for (int k = 0; k < 4; ++k) {
            const int j = k * 256 + t;
            const int r = j >> 5;
            out4[((size_t)(b * L_ + q0 + r) * H_ + h) * 32 + (t & 31)] = vm4;
        }
    }
}

// ---------------- K3: chunked scores + partial softmax + partial PV ----------
// Block map XCD-swizzled: xcd = bid&7 owns 4 bh's 16 blocks (8 kc x 2 uh) so
// the K/V chunk re-reads across uh halves hit the local L2.
__global__ __launch_bounds__(256) void k_scorepv(const float* __restrict__ Q,
                                                 const float* __restrict__ K,
                                                 const float* __restrict__ V,
                                                 const int* __restrict__ topk,
                                                 float* __restrict__ pmax,
                                                 float* __restrict__ psum,
                                                 float* __restrict__ pout) {
    __shared__ float Qs[20 * D_];           // 10 KB
    __shared__ float S[20 * 260];           // 20.3 KB
    __shared__ float mrow[20];
    __shared__ int   tq[20];
    const int bid = blockIdx.x;
    const int xcd = bid & 7;
    const int loc = bid >> 3;               // 0..63
    const int bh  = (xcd << 2) + (loc >> 4);
    const int sub16 = loc & 15;
    const int kc  = sub16 >> 1;
    const int uh  = sub16 & 1;
    const int h   = bh & (H_ - 1);
    const int b   = bh >> 4;
    const int t   = threadIdx.x;

    if (t < 20) tq[t] = topk[bh * NTOP_ + uh * 20 + t];
    __syncthreads();

    {
        const float4* Q4 = (const float4*)Q;
        float4* Qs4 = (float4*)Qs;
        #pragma unroll
        for (int it = 0; it < 3; ++it) {
            const int i = it * 256 + t;
            if (i < 640) {
                const int u = i >> 5, dc = i & 31;
                Qs4[i] = Q4[((size_t)(b * L_ + tq[u]) * H_ + h) * 32 + dc];
            }
        }
    }
    __syncthreads();

    {
        float acc[20];
        #pragma unroll
        for (int u = 0; u < 20; ++u) acc[u] = 0.0f;
        const float4* Kb = (const float4*)K + ((size_t)(b * L_ + kc * CHK_ + t) * H_ + h) * 32;
        const float4* Qs4 = (const float4*)Qs;
        for (int dc = 0; dc < 32; ++dc) {
            const float4 kv = Kb[dc];
            #pragma unroll
            for (int u = 0; u < 20; ++u) {
                const float4 qv = Qs4[u * 32 + dc];
                acc[u] += qv.x * kv.x + qv.y * kv.y + qv.z * kv.z + qv.w * kv.w;
            }
        }
        #pragma unroll
        for (int u = 0; u < 20; ++u) S[u * 260 + t] = acc[u] * SCALE_;
    }
    __syncthreads();

    {
        const int w = t >> 6, lane = t & 63;
        #pragma unroll
        for (int uu = 0; uu < 5; ++uu) {
            const int u = w * 5 + uu;
            const float* Sr = S + u * 260;
            float v = fmaxf(fmaxf(Sr[lane], Sr[lane + 64]),
                            fmaxf(Sr[lane + 128], Sr[lane + 192]));
            #pragma unroll
            for (int o = 1; o < 64; o <<= 1) v = fmaxf(v, __shfl_xor(v, o, 64));
            if (lane == 0) mrow[u] = v;
        }
    }
    __syncthreads();

    #pragma unroll
    for (int u = 0; u < 20; ++u) S[u * 260 + t] = __expf(S[u * 260 + t] - mrow[u]);
    __syncthreads();

    {
        const int w = t >> 6, lane = t & 63;
        #pragma unroll
        for (int uu = 0; uu < 5; ++uu) {
            const int u = w * 5 + uu;
            const float* Sr = S + u * 260;
            float v = Sr[lane] + Sr[lane + 64] + Sr[lane + 128] + Sr[lane + 192];
            #pragma unroll
            for (int o = 1; o < 64; o <<= 1) v += __shfl_xor(v, o, 64);
            if (lane == 0) {
                psum[(bh * NCH_ + kc) * NTOP_ + uh * 20 + u] = v;
                pmax[(bh * NCH_ + kc) * NTOP_ + uh * 20 + u] = mrow[u];
            }
        }
    }

    {
        const int d  = t & (D_ - 1);
        const int g  = t >> 7;
        const int u0 = g * 10;
        float acc2[10];
        #pragma unroll
        for (int u = 0; u < 10; ++u) acc2[u] = 0.0f;
        const float* Vb = V + ((size_t)(b * L_ + kc * CHK_) * H_ + h) * D_ + d;
        for (int kq = 0; kq < CHK_ / 4; ++kq) {
            const float v0 = Vb[(size_t)(kq * 4 + 0) * (H_ * D_)];
            const float v1 = Vb[(size_t)(kq * 4 + 1) * (H_ * D_)];
            const float v2 = Vb[(size_t)(kq * 4 + 2) * (H_ * D_)];
            const float v3 = Vb[(size_t)(kq * 4 + 3) * (H_ * D_)];
            #pragma unroll
            for (int u = 0; u < 10; ++u) {
                const float4 p = *(const float4*)&S[(u0 + u) * 260 + kq * 4];
                acc2[u] += p.x * v0 + p.y * v1 + p.z * v2 + p.w * v3;
            }
        }
        float* pb = pout + (((size_t)(bh * NCH_ + kc)) * NTOP_ + uh * 20 + u0) * D_ + d;
        #pragma unroll
        for (int u = 0; u < 10; ++u) pb[(size_t)u * D_] = acc2[u];
    }
}

// ---------------- K4: combine chunk partials, scatter to out -----------------
__global__ __launch_bounds__(128) void k_comb(const float* __restrict__ pmax,
                                              const float* __restrict__ psum,
                                              const float* __restrict__ pout,
                                              const int* __restrict__ topk,
                                              float* __restrict__ out) {
    const int bid = blockIdx.x;          // bh*40 + u
    const int bh  = bid / NTOP_;
    const int u   = bid - bh * NTOP_;
    const int h   = bh & (H_ - 1);
    const int b   = bh >> 4;
    const int t   = threadIdx.x;         // d

    float pm[NCH_];
    float M = -INFINITY;
    #pragma unroll
    for (int c = 0; c < NCH_; ++c) {
        pm[c] = pmax[(bh * NCH_ + c) * NTOP_ + u];
        M = fmaxf(M, pm[c]);
    }
    float ssum = 0.0f, o = 0.0f;
    #pragma unroll
    for (int c = 0; c < NCH_; ++c) {
        const float w = __expf(pm[c] - M);
        ssum += psum[(bh * NCH_ + c) * NTOP_ + u] * w;
        o += pout[((size_t)(bh * NCH_ + c) * NTOP_ + u) * D_ + t] * w;
    }
    const int qi = topk[bh * NTOP_ + u];
    out[((size_t)(b * L_ + qi) * H_ + h) * D_ + t] = o / ssum;
}

extern "C" void kernel_launch(void* const* d_in, const int* in_sizes, int n_in,
                              void* d_out, int out_size, void* d_ws, size_t ws_size,
                              hipStream_t stream) {
    const float* Q  = (const float*)d_in[0];
    const float* K  = (const float*)d_in[1];
    const float* V  = (const float*)d_in[2];
    const int* idx  = (const int*)d_in[3];
    float* out      = (float*)d_out;

    char* ws = (char*)d_ws;
    size_t off = 0;
    float* Mws   = (float*)(ws + off); off += (size_t)65536 * 4;
    float* vpart = (float*)(ws + off); off += (size_t)1024 * 128 * 4;
    int*   cnt   = (int*)(ws + off);   off += 32 * 4;
    int*   topk  = (int*)(ws + off);   off += 1280 * 4;
    float* pmax  = (float*)(ws + off); off += (size_t)256 * 40 * 4;
    float* psum  = (float*)(ws + off); off += (size_t)256 * 40 * 4;
    float* pout  = (float*)(ws + off); off += (size_t)256 * 40 * 128 * 4;

    hipLaunchKernelGGL(k1_sample_vpart, dim3(NVP_BLKS + NSAMP_BLKS), dim3(256), 0, stream,
                       Q, K, V, idx, Mws, vpart, cnt);
    hipLaunchKernelGGL(k2_rank_fill,    dim3(256 + 2048), dim3(256), 0, stream,
                       Mws, vpart, cnt, topk, out);
    hipLaunchKernelGGL(k_scorepv,       dim3(512),  dim3(256), 0, stream,
                       Q, K, V, topk, pmax, psum, pout);
    hipLaunchKernelGGL(k_comb,          dim3(1280), dim3(128), 0, stream,
                       pmax, psum, pout, topk, out);
}

// Round 8
// 135.809 us; speedup vs baseline: 2.6717x; 1.3542x over previous
//
#include <hip/hip_runtime.h>
#include <math.h>

#define B_    2
#define L_    2048
#define H_    16
#define D_    128
#define S_    40
#define NTOP_ 40
#define NCH_  8        // key chunks for attention
#define CHK_  256      // keys per chunk (attention)
#define VCH_  32       // L chunks for vmean

#define SCALE_ 0.08838834764831843f  // 1/sqrt(128)

#define NVP_BLKS   1024    // vpartial blocks (first, to overlap)
#define NSAMP_BLKS 16384   // sampleM: 4 rows per block (1 per wave)

// ---------------- K1: fused vpartial + sampleM -------------------------------
// blocks 0..1023: V partial sums. block 0 zeroes the rank counters.
// blocks 1024..17407: sampleM, one wave per q-row; 8 lanes span D (16 f/lane).
// All 20 K gathers + 4 Q loads issued BEFORE a sched_barrier(0) so the
// compiler cannot sink them into the compute -> ~20 loads in flight per wave
// (r7 showed VGPR=32: loads were being serialized ~5 at a time).
// XCD-aware: xcd = sb&7 owns bh in [xcd*4, xcd*4+4).
__global__ __launch_bounds__(256) void k1_sample_vpart(const float* __restrict__ Q,
                                                       const float* __restrict__ K,
                                                       const float* __restrict__ V,
                                                       const int* __restrict__ idx,
                                                       float* __restrict__ M,
                                                       float* __restrict__ vpart,
                                                       int* __restrict__ cnt) {
    const int bid = blockIdx.x;
    const int t   = threadIdx.x;

    if (bid < NVP_BLKS) {
        __shared__ float red[256];
        if (bid == 0 && t < 32) cnt[t] = 0;
        const int vbid = bid;                // bh*VCH_ + lc
        const int bh  = vbid >> 5;
        const int lc  = vbid & (VCH_ - 1);
        const int h   = bh & (H_ - 1);
        const int b   = bh >> 4;
        const int d   = t & (D_ - 1);
        const int sub = t >> 7;
        float acc = 0.0f;
        const int l0 = lc * (L_ / VCH_);     // 64 rows per chunk
        for (int l = l0 + sub; l < l0 + L_ / VCH_; l += 2)
            acc += V[((size_t)(b * L_ + l) * H_ + h) * D_ + d];
        red[t] = acc;
        __syncthreads();
        if (t < D_) vpart[(size_t)vbid * D_ + t] = red[t] + red[t + 128];
        return;
    }

    const int sb   = bid - NVP_BLKS;
    const int xcd  = sb & 7;
    const int li   = sb >> 3;                 // 0..2047
    const int bh   = (xcd << 2) + (li >> 9);  // 4 bh per XCD
    const int rb   = li & 511;                // 512 row-blocks per bh
    const int wave = t >> 6;
    const int lane = t & 63;
    const int q    = rb * 4 + wave;
    const int h    = bh & (H_ - 1);
    const int b    = bh >> 4;
    const int g    = lane >> 3;               // 0..7 : sample within slot
    const int sub  = lane & 7;                // float4 within D

    const float4* Q4 = (const float4*)Q;
    const float4* K4 = (const float4*)K;
    const size_t rowQ = ((size_t)(b * L_ + q) * H_ + h) * 32;
    const size_t kbase = ((size_t)b * L_ * H_ + h) * 32 + sub;  // + ki*(H_*32)
    const int* ip = idx + q * S_;

    int kidx[5];
    #pragma unroll
    for (int s = 0; s < 5; ++s) kidx[s] = ip[s * 8 + g];

    const float4 qv0 = Q4[rowQ + 0  + sub];
    const float4 qv1 = Q4[rowQ + 8  + sub];
    const float4 qv2 = Q4[rowQ + 16 + sub];
    const float4 qv3 = Q4[rowQ + 24 + sub];

    float4 kv[5][4];   // all 20 gathers issued before the barrier
    #pragma unroll
    for (int s = 0; s < 5; ++s) {
        const float4* kb = K4 + kbase + (size_t)kidx[s] * (H_ * 32);
        kv[s][0] = kb[0];
        kv[s][1] = kb[8];
        kv[s][2] = kb[16];
        kv[s][3] = kb[24];
    }
    __builtin_amdgcn_sched_barrier(0);

    float smax = -INFINITY, ssum = 0.0f;
    #pragma unroll
    for (int s = 0; s < 5; ++s) {
        float p = qv0.x * kv[s][0].x + qv0.y * kv[s][0].y + qv0.z * kv[s][0].z + qv0.w * kv[s][0].w
                + qv1.x * kv[s][1].x + qv1.y * kv[s][1].y + qv1.z * kv[s][1].z + qv1.w * kv[s][1].w
                + qv2.x * kv[s][2].x + qv2.y * kv[s][2].y + qv2.z * kv[s][2].z + qv2.w * kv[s][2].w
                + qv3.x * kv[s][3].x + qv3.y * kv[s][3].y + qv3.z * kv[s][3].z + qv3.w * kv[s][3].w;
        p += __shfl_xor(p, 1);
        p += __shfl_xor(p, 2);
        p += __shfl_xor(p, 4);
        smax = fmaxf(smax, p);
        ssum += p;
    }
    #pragma unroll
    for (int o = 8; o < 64; o <<= 1) {
        smax = fmaxf(smax, __shfl_xor(smax, o));
        ssum += __shfl_xor(ssum, o);
    }
    if (lane == 0) M[(size_t)bh * L_ + q] = smax - ssum * (1.0f / L_);
}

// ---------------- K2: radix top-40 + broadcast fill --------------------------
// blocks 0..31: per-bh 4-level radix select of the exact 40th-largest value
//   (monotone-uint encoding), then select {ue > T40} plus the `rem` smallest-
//   index elements with ue == T40 -> exactly jax.lax.top_k's selected SET.
// blocks 32..2079: fill out with vmean (folded locally from vpart).
__global__ __launch_bounds__(256) void k2_rank_fill(const float* __restrict__ M,
                                                    const float* __restrict__ vpart,
                                                    int* __restrict__ cnt,
                                                    int* __restrict__ topk,
                                                    float* __restrict__ out) {
    __shared__ unsigned int ue[L_];
    __shared__ int hist[256], sscan[256];
    __shared__ int eqlist[256];
    __shared__ int sh_chosen, sh_need, sh_eqcnt;
    __shared__ float mlf[256];
    const int bid = blockIdx.x;
    const int t   = threadIdx.x;

    if (bid < 32) {
        const int bh = bid;
        const float* Mrow = M + (size_t)bh * L_;
        for (int i = t; i < L_; i += 256) {
            const unsigned int ub = __float_as_uint(Mrow[i]);
            ue[i] = (ub & 0x80000000u) ? ~ub : (ub | 0x80000000u);
        }
        if (t == 0) sh_eqcnt = 0;
        __syncthreads();

        unsigned int prefix = 0;
        int need = NTOP_;
        for (int l = 3; l >= 0; --l) {
            hist[t] = 0;
            __syncthreads();
            for (int i = t; i < L_; i += 256) {
                const unsigned int u = ue[i];
                const bool match = (l == 3) || ((u >> (8 * (l + 1))) == prefix);
                if (match) atomicAdd(&hist[(u >> (8 * l)) & 255], 1);
            }
            __syncthreads();
            sscan[t] = hist[t];
            __syncthreads();
            for (int off = 1; off < 256; off <<= 1) {
                const int v = (t + off < 256) ? sscan[t + off] : 0;
                __syncthreads();
                sscan[t] += v;
                __syncthreads();
            }
            const int above = sscan[t] - hist[t];   // count of elems in bins > t
            if (above < need && need <= above + hist[t]) {
                sh_chosen = t;
                sh_need = need - above;
            }
            __syncthreads();
            prefix = (prefix << 8) | (unsigned int)sh_chosen;
            need = sh_need;
            __syncthreads();
        }
        const unsigned int T40 = prefix;
        const int rem = need;                 // how many == T40 to take (lowest idx)

        for (int i = t; i < L_; i += 256) {
            const unsigned int u = ue[i];
            if (u > T40) {
                const int pos = atomicAdd(&cnt[bh], 1);
                topk[bh * NTOP_ + pos] = i;
            } else if (u == T40) {
                const int p = atomicAdd(&sh_eqcnt, 1);
                if (p < 256) eqlist[p] = i;
            }
        }
        __syncthreads();
        const int n = min(sh_eqcnt, 256);
        for (int i = t; i < n; i += 256) {
            const int mye = eqlist[i];
            int rk = 0;
            for (int j = 0; j < n; ++j) rk += (eqlist[j] < mye);
            if (rk < rem) {
                const int pos = atomicAdd(&cnt[bh], 1);
                topk[bh * NTOP_ + pos] = mye;
            }
        }
    } else {
        const int fb = bid - 32;             // 0..2047
        const int bh = fb >> 6;
        const int sl = fb & 63;              // 64 slices of 32 q-rows
        const int h  = bh & (H_ - 1);
        const int b  = bh >> 4;
        const int d    = t & (D_ - 1);
        const int half = t >> 7;
        float s = 0.0f;
        #pragma unroll
        for (int c = half * 16; c < half * 16 + 16; ++c)
            s += vpart[(size_t)(bh * VCH_ + c) * D_ + d];
        mlf[t] = s;
        __syncthreads();
        if (t < D_) mlf[t] = (mlf[t] + mlf[t + 128]) * (1.0f / L_);
        __syncthreads();
        const float4 vm4 = *(const float4*)&mlf[(t & 31) * 4];
        float4* out4 = (float4*)out;
        const int q0 = sl * 32;
        #pragma unroll
        for (int k = 0; k < 4; ++k) {
            const int j = k * 256 + t;
            const int r = j >> 5;
            out4[((size_t)(b * L_ + q0 + r) * H_ + h) * 32 + (t & 31)] = vm4;
        }
    }
}

// ---------------- K3: LDS-staged scores + partial softmax + partial PV -------
// Block = (bh, kc, uh), XCD-swizzled. Score phase: K staged in 4 LDS passes of
// 64 rows (stride 33 float4; b128 reads along r sit at the 8-phase bank floor);
// thread = (key r, u-quarter), acc[5]; Q reads are broadcasts. Removes the
// 64-scattered-segment global K loads of the gather variant.
__global__ __launch_bounds__(256) void k_scorepv(const float* __restrict__ Q,
                                                 const float* __restrict__ K,
                                                 const float* __restrict__ V,
                                                 const int* __restrict__ topk,
                                                 float* __restrict__ pmax,
                                                 float* __restrict__ psum,
                                                 float* __restrict__ pout) {
    __shared__ float Qs[20 * D_];           // 10 KB
    __shared__ float S[20 * 260];           // 20.3 KB
    __shared__ float Ks[64 * 132];          // 33.8 KB
    __shared__ float mrow[20];
    __shared__ int   tq[20];
    const int bid = blockIdx.x;
    const int xcd = bid & 7;
    const int loc = bid >> 3;               // 0..63
    const int bh  = (xcd << 2) + (loc >> 4);
    const int sub16 = loc & 15;
    const int kc  = sub16 >> 1;
    const int uh  = sub16 & 1;
    const int h   = bh & (H_ - 1);
    const int b   = bh >> 4;
    const int t   = threadIdx.x;

    if (t < 20) tq[t] = topk[bh * NTOP_ + uh * 20 + t];
    __syncthreads();

    {
        const float4* Q4 = (const float4*)Q;
        float4* Qs4 = (float4*)Qs;
        #pragma unroll
        for (int it = 0; it < 3; ++it) {
            const int i = it * 256 + t;
            if (i < 640) {
                const int u = i >> 5, dc = i & 31;
                Qs4[i] = Q4[((size_t)(b * L_ + tq[u]) * H_ + h) * 32 + dc];
            }
        }
    }
    __syncthreads();

    // scores: 4 staged passes of 64 keys
    {
        const float4* K4 = (const float4*)K;
        const float4* Qs4 = (const float4*)Qs;
        float4* Ks4 = (float4*)Ks;
        const int r = t & 63, uq = t >> 6;
        for (int pass = 0; pass < 4; ++pass) {
            #pragma unroll
            for (int j = 0; j < 8; ++j) {
                const int gidx = j * 256 + t;
                const int row = gidx >> 5, c = gidx & 31;
                Ks4[row * 33 + c] =
                    K4[((size_t)(b * L_ + kc * CHK_ + pass * 64 + row) * H_ + h) * 32 + c];
            }
            __syncthreads();
            float acc[5] = {0.f, 0.f, 0.f, 0.f, 0.f};
            for (int dc = 0; dc < 32; ++dc) {
                const float4 kv = Ks4[r * 33 + dc];
                #pragma unroll
                for (int u5 = 0; u5 < 5; ++u5) {
                    const float4 qv = Qs4[(uq * 5 + u5) * 32 + dc];
                    acc[u5] += qv.x * kv.x + qv.y * kv.y + qv.z * kv.z + qv.w * kv.w;
                }
            }
            #pragma unroll
            for (int u5 = 0; u5 < 5; ++u5)
                S[(uq * 5 + u5) * 260 + pass * 64 + r] = acc[u5] * SCALE_;
            __syncthreads();
        }
    }

    {
        const int w = t >> 6, lane = t & 63;
        #pragma unroll
        for (int uu = 0; uu < 5; ++uu) {
            const int u = w * 5 + uu;
            const float* Sr = S + u * 260;
            float v = fmaxf(fmaxf(Sr[lane], Sr[lane + 64]),
                            fmaxf(Sr[lane + 128], Sr[lane + 192]));
            #pragma unroll
            for (int o = 1; o < 64; o <<= 1) v = fmaxf(v, __shfl_xor(v, o, 64));
            if (lane == 0) mrow[u] = v;
        }
    }
    __syncthreads();

    #pragma unroll
    for (int u = 0; u < 20; ++u) S[u * 260 + t] = __expf(S[u * 260 + t] - mrow[u]);
    __syncthreads();

    {
        const int w = t >> 6, lane = t & 63;
        #pragma unroll
        for (int uu = 0; uu < 5; ++uu) {
            const int u = w * 5 + uu;
            const float* Sr = S + u * 260;
            float v = Sr[lane] + Sr[lane + 64] + Sr[lane + 128] + Sr[lane + 192];
            #pragma unroll
            for (int o = 1; o < 64; o <<= 1) v += __shfl_xor(v, o, 64);
            if (lane == 0) {
                psum[(bh * NCH_ + kc) * NTOP_ + uh * 20 + u] = v;
                pmax[(bh * NCH_ + kc) * NTOP_ + uh * 20 + u] = mrow[u];
            }
        }
    }

    {
        const int d  = t & (D_ - 1);
        const int g  = t >> 7;
        const int u0 = g * 10;
        float acc2[10];
        #pragma unroll
        for (int u = 0; u < 10; ++u) acc2[u] = 0.0f;
        const float* Vb = V + ((size_t)(b * L_ + kc * CHK_) * H_ + h) * D_ + d;
        for (int kq = 0; kq < CHK_ / 4; ++kq) {
            const float v0 = Vb[(size_t)(kq * 4 + 0) * (H_ * D_)];
            const float v1 = Vb[(size_t)(kq * 4 + 1) * (H_ * D_)];
            const float v2 = Vb[(size_t)(kq * 4 + 2) * (H_ * D_)];
            const float v3 = Vb[(size_t)(kq * 4 + 3) * (H_ * D_)];
            #pragma unroll
            for (int u = 0; u < 10; ++u) {
                const float4 p = *(const float4*)&S[(u0 + u) * 260 + kq * 4];
                acc2[u] += p.x * v0 + p.y * v1 + p.z * v2 + p.w * v3;
            }
        }
        float* pb = pout + (((size_t)(bh * NCH_ + kc)) * NTOP_ + uh * 20 + u0) * D_ + d;
        #pragma unroll
        for (int u = 0; u < 10; ++u) pb[(size_t)u * D_] = acc2[u];
    }
}

// ---------------- K4: combine chunk partials, scatter to out -----------------
__global__ __launch_bounds__(128) void k_comb(const float* __restrict__ pmax,
                                              const float* __restrict__ psum,
                                              const float* __restrict__ pout,
                                              const int* __restrict__ topk,
                                              float* __restrict__ out) {
    const int bid = blockIdx.x;          // bh*40 + u
    const int bh  = bid / NTOP_;
    const int u   = bid - bh * NTOP_;
    const int h   = bh & (H_ - 1);
    const int b   = bh >> 4;
    const int t   = threadIdx.x;         // d

    float pm[NCH_];
    float M = -INFINITY;
    #pragma unroll
    for (int c = 0; c < NCH_; ++c) {
        pm[c] = pmax[(bh * NCH_ + c) * NTOP_ + u];
        M = fmaxf(M, pm[c]);
    }
    float ssum = 0.0f, o = 0.0f;
    #pragma unroll
    for (int c = 0; c < NCH_; ++c) {
        const float w = __expf(pm[c] - M);
        ssum += psum[(bh * NCH_ + c) * NTOP_ + u] * w;
        o += pout[((size_t)(bh * NCH_ + c) * NTOP_ + u) * D_ + t] * w;
    }
    const int qi = topk[bh * NTOP_ + u];
    out[((size_t)(b * L_ + qi) * H_ + h) * D_ + t] = o / ssum;
}

extern "C" void kernel_launch(void* const* d_in, const int* in_sizes, int n_in,
                              void* d_out, int out_size, void* d_ws, size_t ws_size,
                              hipStream_t stream) {
    const float* Q  = (const float*)d_in[0];
    const float* K  = (const float*)d_in[1];
    const float* V  = (const float*)d_in[2];
    const int* idx  = (const int*)d_in[3];
    float* out      = (float*)d_out;

    char* ws = (char*)d_ws;
    size_t off = 0;
    float* Mws   = (float*)(ws + off); off += (size_t)65536 * 4;
    float* vpart = (float*)(ws + off); off += (size_t)1024 * 128 * 4;
    int*   cnt   = (int*)(ws + off);   off += 32 * 4;
    int*   topk  = (int*)(ws + off);   off += 1280 * 4;
    float* pmax  = (float*)(ws + off); off += (size_t)256 * 40 * 4;
    float* psum  = (float*)(ws + off); off += (size_t)256 * 40 * 4;
    float* pout  = (float*)(ws + off); off += (size_t)256 * 40 * 128 * 4;

    hipLaunchKernelGGL(k1_sample_vpart, dim3(NVP_BLKS + NSAMP_BLKS), dim3(256), 0, stream,
                       Q, K, V, idx, Mws, vpart, cnt);
    hipLaunchKernelGGL(k2_rank_fill,    dim3(32 + 2048), dim3(256), 0, stream,
                       Mws, vpart, cnt, topk, out);
    hipLaunchKernelGGL(k_scorepv,       dim3(512),  dim3(256), 0, stream,
                       Q, K, V, topk, pmax, psum, pout);
    hipLaunchKernelGGL(k_comb,          dim3(1280), dim3(128), 0, stream,
                       pmax, psum, pout, topk, out);
}